// Round 15
// baseline (534.489 us; speedup 1.0000x reference)
//
#include <hip/hip_runtime.h>
#include <math.h>

#define HEADS 4
#define HD 32      // per-head out dim
#define QD 64      // type query dim
#define DIN 128    // in_dim == hidden_dim
#define NTYPES 4
#define ETYPES 3
#define CAP 512    // per-edge LDS logit capacity (max segment ~85 for this data)
#define WTC 272    // Wt columns per layer: 0..127 fc1, 128..255 Wv, 256..267 Wqc(logit)

typedef __attribute__((ext_vector_type(8))) short bf16x8;
typedef __attribute__((ext_vector_type(4))) float f32x4;
typedef unsigned short ushort_t;

static inline int cdiv(int a, int b){ return (a + b - 1) / b; }

__device__ inline unsigned short f2bf(float f){
  unsigned u = __float_as_uint(f);
  unsigned r = (u + 0x7FFF + ((u >> 16) & 1)) >> 16;   // RNE
  return (unsigned short)r;
}
__device__ inline float bf2f(unsigned short u){ return __uint_as_float(((unsigned)u) << 16); }

// lgt layout: [n][et][h] bf16, row = 12 ushorts = 24B; one uint2 = all 4 heads of (n,et)
__device__ inline float lgt_get(const ushort_t* __restrict__ lgt, int n, int et, int hh){
  uint2 lg = *(const uint2*)((const char*)lgt + (size_t)n*24 + et*8);
  unsigned u = (hh & 2) ? lg.y : lg.x;
  return bf2f((hh & 1) ? (ushort_t)(u >> 16) : (ushort_t)(u & 0xffff));
}

__device__ inline void accum8(float* ef, uint4 w, float e){
  ef[0] += e*bf2f((ushort_t)(w.x & 0xffff)); ef[1] += e*bf2f((ushort_t)(w.x >> 16));
  ef[2] += e*bf2f((ushort_t)(w.y & 0xffff)); ef[3] += e*bf2f((ushort_t)(w.y >> 16));
  ef[4] += e*bf2f((ushort_t)(w.z & 0xffff)); ef[5] += e*bf2f((ushort_t)(w.z >> 16));
  ef[6] += e*bf2f((ushort_t)(w.w & 0xffff)); ef[7] += e*bf2f((ushort_t)(w.w >> 16));
}

// ---------------- preprocessing ----------------

// hist into concatenated [cnt_e | cnt_n] (size E+N); atomics double as sort ranks.
__global__ __launch_bounds__(256) void hist_k(const int* __restrict__ node_idx,
                                              const int* __restrict__ edge_idx,
                                              int* __restrict__ cnt,  // [E+N]
                                              uint2* __restrict__ ranks, int E, int NNZ)
{
  int i = blockIdx.x*256 + threadIdx.x;
  if (i < NNZ){
    unsigned re = (unsigned)atomicAdd(&cnt[edge_idx[i]], 1);
    unsigned rn = (unsigned)atomicAdd(&cnt[E + node_idx[i]], 1);
    uint2 r; r.x = re; r.y = rn;
    ranks[i] = r;
  }
}

__global__ __launch_bounds__(1024) void scan_pass1(const int* __restrict__ in, int* __restrict__ bsums, int n)
{
  __shared__ int sd[1024];
  int i = blockIdx.x*1024 + threadIdx.x;
  sd[threadIdx.x] = (i < n) ? in[i] : 0;
  __syncthreads();
  for (int s = 512; s > 0; s >>= 1){
    if (threadIdx.x < s) sd[threadIdx.x] += sd[threadIdx.x + s];
    __syncthreads();
  }
  if (threadIdx.x == 0) bsums[blockIdx.x] = sd[0];
}

__global__ __launch_bounds__(1024) void scan_pass2(int* __restrict__ bsums, int nb)
{
  __shared__ int sd[1024];
  int v = (threadIdx.x < nb) ? bsums[threadIdx.x] : 0;
  sd[threadIdx.x] = v;
  __syncthreads();
  for (int s = 1; s < 1024; s <<= 1){
    int t = (threadIdx.x >= s) ? sd[threadIdx.x - s] : 0;
    __syncthreads();
    sd[threadIdx.x] += t;
    __syncthreads();
  }
  if (threadIdx.x < nb) bsums[threadIdx.x] = sd[threadIdx.x] - v;  // exclusive
}

__global__ __launch_bounds__(1024) void scan_pass3(const int* __restrict__ in, const int* __restrict__ bsums,
                                                   int* __restrict__ out, int n)
{
  __shared__ int sd[1024];
  int i = blockIdx.x*1024 + threadIdx.x;
  int v = (i < n) ? in[i] : 0;
  sd[threadIdx.x] = v;
  __syncthreads();
  for (int s = 1; s < 1024; s <<= 1){
    int t = (threadIdx.x >= s) ? sd[threadIdx.x - s] : 0;
    __syncthreads();
    sd[threadIdx.x] += t;
    __syncthreads();
  }
  if (i < n) out[i] = bsums[blockIdx.x] + sd[threadIdx.x] - v;  // exclusive offsets
}

// Scatter: atomic-free; single scattered 8B store per entry.
__global__ __launch_bounds__(256) void scatter_k(const int* __restrict__ node_idx, const int* __restrict__ edge_idx,
                                                 const uint2* __restrict__ ranks,
                                                 const int* __restrict__ off,
                                                 uint2* __restrict__ srtE_rec, int E, int NNZ)
{
  int i = blockIdx.x*256 + threadIdx.x;
  if (i >= NNZ) return;
  int n = node_idx[i], e = edge_idx[i];
  uint2 r = ranks[i];
  int pe = off[e] + (int)r.x;
  int pn = off[E + n] - NNZ + (int)r.y;
  uint2 rec; rec.x = (unsigned)n; rec.y = (unsigned)pn;
  srtE_rec[pe] = rec;
}

// ---------------- weight prep ----------------

// Wt cols 0..127: fc1 (hh=c>>5, j=c&31); 128..255: Wv
__global__ __launch_bounds__(128) void wtprep_k(const float* __restrict__ w1, const float* __restrict__ wv,
                                                short* __restrict__ Wt, int L)
{
  int c = blockIdx.x % 256, l = blockIdx.x / 256;
  int k = threadIdx.x;
  int hh = (c >> 5) & 3, j = c & 31;
  float v;
  if (c < 128) v = w1[((((size_t)l*HEADS + hh)*(DIN+QD)) + k)*32 + j];
  else         v = wv[((((size_t)l*HEADS + hh)*DIN) + k)*32 + j];
  Wt[((size_t)l*WTC + c)*128 + k] = (short)f2bf(v);
}

// Wqc logit columns: Wt[l][256 + h*3+et][k] = sum_d wq[l][h][k][d] * ec[l][h][et][d]
__global__ __launch_bounds__(128) void wqc_k(const float* __restrict__ wq, const float* __restrict__ ec,
                                             short* __restrict__ Wt)
{
  int b = blockIdx.x;                 // l*12 + h*3 + et
  int l = b / 12, c = b % 12, h = c / 3, et = c % 3;
  int k = threadIdx.x;
  const float* wrow = wq + ((((size_t)l*HEADS + h)*DIN) + k)*32;
  const float* ecp  = ec + (((size_t)l*HEADS + h)*ETYPES + et)*32;
  float s = 0.f;
  #pragma unroll
  for (int d = 0; d < 32; d++) s += wrow[d] * ecp[d];
  Wt[((size_t)l*WTC + 256 + c)*128 + k] = (short)f2bf(s);
}

// sbias[l][hh][ty][j] = b1 + sig @ w1[128:192]
__global__ __launch_bounds__(32) void sbias_k(const float* __restrict__ tq, const float* __restrict__ w1,
                                              const float* __restrict__ b1, float* __restrict__ sbias)
{
  int b = blockIdx.x;
  int ty = b % NTYPES; int hh = (b / NTYPES) % HEADS; int l = b / (NTYPES*HEADS);
  int j = threadIdx.x;
  const float* tqp = tq + (((size_t)l*HEADS + hh)*NTYPES + ty)*QD;
  const float* w1p = w1 + ((size_t)l*HEADS + hh)*(DIN+QD)*32;
  float s = b1[((size_t)l*HEADS + hh)*32 + j];
  for (int k = 0; k < QD; k++) s += tqp[k] * w1p[(size_t)(DIN + k)*32 + j];
  sbias[(size_t)b*32 + j] = s;
}

// ---------------- fused gemm (LDS-staged): h read ONCE -> {alpha->lgt, vb} ----------------
// 512 threads = 8 waves: wave (wr=wvid>>2, wc=wvid&3). rows wr*64..; wc 0,1 -> fc1 cols wc*64;
// wc 2,3 -> Wv cols (wc-2)*64. wc==0 waves also accumulate the 12 logit columns.
// h tile staged once to LDS as bf16 [128][136] (pad 8 -> 2-way-free banks, 16B-aligned rows).

__global__ __launch_bounds__(512) void gemm_f3(
    const float* __restrict__ h, int hstride,
    const short* __restrict__ Wt,          // this layer
    const int* __restrict__ node_types,
    const float* __restrict__ sbias,       // [H][NTYPES][32]
    const float* __restrict__ w2,          // [H][32]
    const float* __restrict__ b2,          // [H]
    ushort_t* __restrict__ lgt,            // [N][ET][H] bf16
    ushort_t* __restrict__ vb,             // [H][N][32] bf16
    int N)
{
  __shared__ ushort_t hlds[128][136];
  __shared__ float alds[128][HEADS];
  int t = threadIdx.x;
  int lane = t & 63, wvid = t >> 6;
  int wr = wvid >> 2, wc = wvid & 3;
  int l15 = lane & 15, l4 = lane >> 4;
  int rbase0 = blockIdx.x*128;
  int rbase = rbase0 + wr*64;

  // stage: 128 rows x 128 f32 -> bf16 LDS; h read exactly once per block
  #pragma unroll
  for (int it = 0; it < 8; it++){
    int idx = it*512 + t;
    int r = idx >> 5, c4 = (idx & 31)*4;
    int rr = rbase0 + r; rr = (rr < N) ? rr : (N-1);
    float4 f = *(const float4*)(h + (size_t)rr*hstride + c4);
    ushort_t* p = &hlds[r][c4];
    p[0] = f2bf(f.x); p[1] = f2bf(f.y); p[2] = f2bf(f.z); p[3] = f2bf(f.w);
  }
  __syncthreads();

  f32x4 acc[4][4] = {};
  f32x4 acc_e[4] = {};
  int colbase = (wc < 2) ? wc*64 : (128 + (wc - 2)*64);

  #pragma unroll
  for (int kk = 0; kk < 4; kk++){
    bf16x8 a[4], b[4];
    #pragma unroll
    for (int mf = 0; mf < 4; mf++)
      a[mf] = *(const bf16x8*)&hlds[wr*64 + mf*16 + l15][kk*32 + l4*8];
    #pragma unroll
    for (int cf = 0; cf < 4; cf++){
      int col = colbase + cf*16 + l15;
      b[cf] = *(const bf16x8*)(Wt + (size_t)col*128 + kk*32 + l4*8);
    }
    #pragma unroll
    for (int mf = 0; mf < 4; mf++)
      #pragma unroll
      for (int cf = 0; cf < 4; cf++)
        acc[mf][cf] = __builtin_amdgcn_mfma_f32_16x16x32_bf16(a[mf], b[cf], acc[mf][cf], 0, 0, 0);
    if (wc == 0){
      int ecol = 256 + ((l15 < 12) ? l15 : 11);
      bf16x8 be = *(const bf16x8*)(Wt + (size_t)ecol*128 + kk*32 + l4*8);
      #pragma unroll
      for (int mf = 0; mf < 4; mf++)
        acc_e[mf] = __builtin_amdgcn_mfma_f32_16x16x32_bf16(a[mf], be, acc_e[mf], 0, 0, 0);
    }
  }

  if (wc < 2){
    // fc1 epilogue -> alpha into LDS (wave wc covers heads wc*2, wc*2+1 for its row half)
    #pragma unroll
    for (int mf = 0; mf < 4; mf++){
      int rw[4], ty[4];
      #pragma unroll
      for (int r = 0; r < 4; r++){
        rw[r] = rbase + mf*16 + l4*4 + r;
        ty[r] = (rw[r] < N) ? node_types[rw[r]] : 0;
      }
      #pragma unroll
      for (int p = 0; p < 2; p++){
        int hh = wc*2 + p;
        float w2a = w2[hh*32 + l15];
        float w2b = w2[hh*32 + 16 + l15];
        float b2v = b2[hh];
        #pragma unroll
        for (int r = 0; r < 4; r++){
          const float* sb = sbias + ((size_t)hh*NTYPES + ty[r])*32;
          float z0 = acc[mf][2*p  ][r] + sb[l15];
          float z1 = acc[mf][2*p+1][r] + sb[16 + l15];
          float t0 = 1.f - 2.f/(__expf(2.f*z0) + 1.f);   // tanh
          float t1 = 1.f - 2.f/(__expf(2.f*z1) + 1.f);
          float val = t0*w2a + t1*w2b;
          val += __shfl_xor(val, 1); val += __shfl_xor(val, 2);
          val += __shfl_xor(val, 4); val += __shfl_xor(val, 8);
          if (l15 == 0)
            alds[wr*64 + mf*16 + l4*4 + r][hh] = 1.f/(1.f + __expf(-(val + b2v)));
        }
      }
    }
  } else {
    // V store epilogue
    #pragma unroll
    for (int mf = 0; mf < 4; mf++){
      #pragma unroll
      for (int r = 0; r < 4; r++){
        int row = rbase + mf*16 + l4*4 + r;
        if (row < N){
          #pragma unroll
          for (int cf = 0; cf < 4; cf++){
            int c = (wc - 2)*64 + cf*16 + l15;   // 0..127
            int hh = c >> 5, d = c & 31;
            vb[((size_t)hh*N + row)*32 + d] = f2bf(acc[mf][cf][r]);
          }
        }
      }
    }
  }
  __syncthreads();

  // logit epilogue (wc==0 waves); D frag: row = l4*4+r, col = l15
  if (wc == 0 && l15 < 12){
    int hq = l15 / 3, et = l15 % 3;
    #pragma unroll
    for (int mf = 0; mf < 4; mf++){
      #pragma unroll
      for (int r = 0; r < 4; r++){
        int rowloc = wr*64 + mf*16 + l4*4 + r;
        int row = rbase0 + rowloc;
        if (row < N){
          float s = acc_e[mf][r] * alds[rowloc][hq];
          s = (s >= 0.f) ? s : 0.2f*s;
          lgt[(size_t)row*12 + et*4 + hq] = f2bf(s);
        }
      }
    }
  }
}

// ---------------- k2b fused: cooperative logit load + segment softmax + edge_feat + attn scatter ----------------

__global__ __launch_bounds__(256) void k2b_f(
    const ushort_t* __restrict__ lgt, const ushort_t* __restrict__ vb,
    const uint2* __restrict__ srtE_rec, const int* __restrict__ edge_off, const int* __restrict__ cnt_e,
    const int* __restrict__ edge_type,
    ushort_t* __restrict__ efb,            // [E][128] bf16
    uint4* __restrict__ attn_rec,          // [NNZ] {e, a01, a23, 0}
    int N, int E)
{
  __shared__ float lbuf[HEADS][CAP];
  __shared__ int   nbuf[CAP];
  __shared__ int   pnbuf[CAP];
  __shared__ float mi[HEADS][2];

  int e = blockIdx.x;
  int off = edge_off[e], cnt = cnt_e[e];
  if (cnt == 0) return;
  int lane = threadIdx.x & 63, hh = threadIdx.x >> 6;
  int et = edge_type[e];

  if (cnt <= CAP){
    for (int j = threadIdx.x; j < cnt; j += 256){
      uint2 rc = srtE_rec[off + j];
      uint2 lg = *(const uint2*)((const char*)lgt + (size_t)rc.x*24 + et*8);
      lbuf[0][j] = bf2f((ushort_t)(lg.x & 0xffff));
      lbuf[1][j] = bf2f((ushort_t)(lg.x >> 16));
      lbuf[2][j] = bf2f((ushort_t)(lg.y & 0xffff));
      lbuf[3][j] = bf2f((ushort_t)(lg.y >> 16));
      nbuf[j] = (int)rc.x;
      pnbuf[j] = (int)rc.y;
    }
    __syncthreads();

    float mloc = -INFINITY;
    for (int j = lane; j < cnt; j += 64) mloc = fmaxf(mloc, lbuf[hh][j]);
    #pragma unroll
    for (int sh = 32; sh > 0; sh >>= 1) mloc = fmaxf(mloc, __shfl_xor(mloc, sh));
    float m = mloc;

    int g4 = lane & 3, grp16 = lane >> 2;
    float ef[8] = {0.f,0.f,0.f,0.f,0.f,0.f,0.f,0.f};
    float ssum = 0.f;
    const int cm1 = cnt - 1;
    const ushort_t* vbh = vb + (size_t)hh*N*32;
    for (int jj = 0; jj < cnt; jj += 64){
      int j0 = jj + grp16, j1 = j0 + 16, j2 = j0 + 32, j3 = j0 + 48;
      int n0 = nbuf[(j0 < cm1) ? j0 : cm1];
      int n1 = nbuf[(j1 < cm1) ? j1 : cm1];
      int n2 = nbuf[(j2 < cm1) ? j2 : cm1];
      int n3 = nbuf[(j3 < cm1) ? j3 : cm1];
      uint4 w0 = *(const uint4*)&vbh[(size_t)n0*32 + 8*g4];
      uint4 w1 = *(const uint4*)&vbh[(size_t)n1*32 + 8*g4];
      uint4 w2 = *(const uint4*)&vbh[(size_t)n2*32 + 8*g4];
      uint4 w3 = *(const uint4*)&vbh[(size_t)n3*32 + 8*g4];
      float e0 = (j0 < cnt) ? __expf(lbuf[hh][j0] - m) : 0.f;
      float e1 = (j1 < cnt) ? __expf(lbuf[hh][j1] - m) : 0.f;
      float e2 = (j2 < cnt) ? __expf(lbuf[hh][j2] - m) : 0.f;
      float e3 = (j3 < cnt) ? __expf(lbuf[hh][j3] - m) : 0.f;
      accum8(ef, w0, e0);
      accum8(ef, w1, e1);
      accum8(ef, w2, e2);
      accum8(ef, w3, e3);
      ssum += e0 + e1 + e2 + e3;
    }
    #pragma unroll
    for (int sh = 4; sh <= 32; sh <<= 1){
      #pragma unroll
      for (int q = 0; q < 8; q++) ef[q] += __shfl_xor(ef[q], sh);
      ssum += __shfl_xor(ssum, sh);
    }
    float inv = 1.0f / ssum;
    if (grp16 == 0){
      uint4 o;
      o.x = (unsigned)f2bf(ef[0]*inv) | ((unsigned)f2bf(ef[1]*inv) << 16);
      o.y = (unsigned)f2bf(ef[2]*inv) | ((unsigned)f2bf(ef[3]*inv) << 16);
      o.z = (unsigned)f2bf(ef[4]*inv) | ((unsigned)f2bf(ef[5]*inv) << 16);
      o.w = (unsigned)f2bf(ef[6]*inv) | ((unsigned)f2bf(ef[7]*inv) << 16);
      *(uint4*)&efb[(size_t)e*128 + hh*32 + 8*g4] = o;
    }
    if (lane == 0){ mi[hh][0] = m; mi[hh][1] = inv; }
    __syncthreads();

    if (hh == 0){
      for (int j = lane; j < cnt; j += 64){
        int pn = pnbuf[j];
        float a0 = __expf(lbuf[0][j] - mi[0][0]) * mi[0][1];
        float a1 = __expf(lbuf[1][j] - mi[1][0]) * mi[1][1];
        float a2 = __expf(lbuf[2][j] - mi[2][0]) * mi[2][1];
        float a3 = __expf(lbuf[3][j] - mi[3][0]) * mi[3][1];
        uint4 o;
        o.x = (unsigned)e;
        o.y = (unsigned)f2bf(a0) | ((unsigned)f2bf(a1) << 16);
        o.z = (unsigned)f2bf(a2) | ((unsigned)f2bf(a3) << 16);
        o.w = 0u;
        attn_rec[pn] = o;
      }
    }
  } else {
    // slow path (cnt > CAP)
    int g = lane & 15, grp = lane >> 4;
    float mloc = -INFINITY;
    for (int j = lane; j < cnt; j += 64)
      mloc = fmaxf(mloc, lgt_get(lgt, (int)srtE_rec[off + j].x, et, hh));
    #pragma unroll
    for (int sh = 32; sh > 0; sh >>= 1) mloc = fmaxf(mloc, __shfl_xor(mloc, sh));
    float m = mloc;

    float ef0 = 0.f, ef1 = 0.f, ssum = 0.f;
    for (int jj = 0; jj < cnt; jj += 4){
      int j = jj + grp;
      if (j < cnt){
        int n = (int)srtE_rec[off + j].x;
        float ex = __expf(lgt_get(lgt, n, et, hh) - m);
        unsigned vw = *(const unsigned*)&vb[((size_t)hh*N + n)*32 + 2*g];
        ef0 += ex * bf2f((unsigned short)(vw & 0xffff));
        ef1 += ex * bf2f((unsigned short)(vw >> 16));
        ssum += ex;
      }
    }
    ef0 += __shfl_xor(ef0, 16); ef0 += __shfl_xor(ef0, 32);
    ef1 += __shfl_xor(ef1, 16); ef1 += __shfl_xor(ef1, 32);
    ssum += __shfl_xor(ssum, 16); ssum += __shfl_xor(ssum, 32);
    float inv = 1.0f / ssum;
    if (grp == 0){
      unsigned w = (unsigned)f2bf(ef0*inv) | ((unsigned)f2bf(ef1*inv) << 16);
      *(unsigned*)&efb[(size_t)e*128 + hh*32 + 2*g] = w;
    }
    for (int j = lane; j < cnt; j += 64){
      uint2 rc = srtE_rec[off + j];
      float ex = __expf(lgt_get(lgt, (int)rc.x, et, hh) - m);
      ushort_t* p = (ushort_t*)&attn_rec[rc.y];
      p[2 + hh] = f2bf(ex * inv);
      if (hh == 0){
        ((unsigned*)p)[0] = (unsigned)e;
        ((unsigned*)p)[3] = 0u;
      }
    }
  }
}

// ---------------- K2c: wave-per-node: shfl-batched gather + residual + wave LayerNorm ----------------

__global__ __launch_bounds__(256) void k2c(
    const uint4* __restrict__ attn_rec,
    const int* __restrict__ node_off, const int* __restrict__ cnt_n, int noff_shift,
    const ushort_t* __restrict__ efb,      // [E][128]
    const float* __restrict__ h_in, int hstride,
    const float* __restrict__ ln_g, const float* __restrict__ ln_b,
    float* __restrict__ out, int out_stride, int out_col, int do_xcopy, int N, int E)
{
  int wv = threadIdx.x >> 6, lane = threadIdx.x & 63;
  int n = blockIdx.x*4 + wv;
  if (n >= N) return;
  int off = node_off[n] - noff_shift, cnt = cnt_n[n];
  int hh = lane >> 4;                 // head owning dims {2*lane, 2*lane+1}
  float nf0 = 0.f, nf1 = 0.f;

  for (int j0 = 0; j0 < cnt; j0 += 8){
    int mm = cnt - j0; if (mm > 8) mm = 8;
    uint4 rc = make_uint4(0u, 0u, 0u, 0u);
    if (lane < mm) rc = attn_rec[off + j0 + lane];
    unsigned w[8]; float av[8];
    #pragma unroll
    for (int j = 0; j < 8; j++){
      unsigned ej = (unsigned)__shfl((int)rc.x, j);
      unsigned ay = (unsigned)__shfl((int)rc.y, j);
      unsigned az = (unsigned)__shfl((int)rc.z, j);
      unsigned u = (hh & 2) ? az : ay;
      float a = bf2f((hh & 1) ? (ushort_t)(u >> 16) : (ushort_t)(u & 0xffff));
      av[j] = (j < mm) ? a : 0.f;
      w[j] = *(const unsigned*)&efb[(size_t)ej*128 + 2*lane];
    }
    #pragma unroll
    for (int j = 0; j < 8; j++){
      nf0 += av[j] * bf2f((ushort_t)(w[j] & 0xffff));
      nf1 += av[j] * bf2f((ushort_t)(w[j] >> 16));
    }
  }

  float2 hr = *(const float2*)&h_in[(size_t)n*hstride + 2*lane];
  if (do_xcopy)
    *(float2*)&out[(size_t)n*out_stride + 2*lane] = hr;   // x into cols 0..127
  float hn0 = nf0 + hr.x, hn1 = nf1 + hr.y;

  float s = hn0 + hn1;
  #pragma unroll
  for (int sh = 32; sh > 0; sh >>= 1) s += __shfl_xor(s, sh);
  float mu = s * (1.0f/128.0f);
  float d0 = hn0 - mu, d1 = hn1 - mu;
  float s2 = d0*d0 + d1*d1;
  #pragma unroll
  for (int sh = 32; sh > 0; sh >>= 1) s2 += __shfl_xor(s2, sh);
  float r = rsqrtf(s2*(1.0f/128.0f) + 1e-5f);

  float2 g2 = *(const float2*)&ln_g[2*lane];
  float2 b2 = *(const float2*)&ln_b[2*lane];
  float2 o2;
  o2.x = d0*r*g2.x + b2.x;
  o2.y = d1*r*g2.y + b2.y;
  *(float2*)&out[(size_t)n*out_stride + out_col + 2*lane] = o2;
}

// ---------------- launcher ----------------

extern "C" void kernel_launch(void* const* d_in, const int* in_sizes, int n_in,
                              void* d_out, int out_size, void* d_ws, size_t ws_size,
                              hipStream_t stream)
{
  const float* x          = (const float*)d_in[0];
  const int*   node_types = (const int*)  d_in[1];
  const int*   node_idx   = (const int*)  d_in[2];
  const int*   edge_idx   = (const int*)  d_in[3];
  const int*   edge_type  = (const int*)  d_in[4];
  const float* type_query = (const float*)d_in[5];
  const float* fc1_w      = (const float*)d_in[6];
  const float* fc1_b      = (const float*)d_in[7];
  const float* fc2_w      = (const float*)d_in[8];
  const float* fc2_b      = (const float*)d_in[9];
  const float* Wq         = (const float*)d_in[10];
  const float* Wv         = (const float*)d_in[11];
  const float* edge_ctx   = (const float*)d_in[12];
  const float* ln_g       = (const float*)d_in[13];
  const float* ln_b       = (const float*)d_in[14];

  const int N   = in_sizes[1];
  const int NNZ = in_sizes[2];
  const int E   = in_sizes[4];
  const int L   = 2;
  const int EN  = E + N;

  char* ws = (char*)d_ws;
  size_t o = 0;
  auto alloc = [&](size_t bytes)->void*{
    void* p = ws + o;
    o = (o + bytes + 255) & ~(size_t)255;
    return p;
  };
  int* cnt       = (int*)alloc((size_t)EN*4);       // [cnt_e | cnt_n]
  int* off       = (int*)alloc((size_t)(EN+1)*4);   // concatenated exclusive scan
  uint2* ranks   = (uint2*)alloc((size_t)NNZ*8);
  uint2* srtE_rec= (uint2*)alloc((size_t)NNZ*8);
  int* bsum      = (int*)alloc((size_t)1024*4);
  uint4* attn_rec = (uint4*)alloc((size_t)NNZ*16);                // [NNZ] {e,a01,a23,0}
  ushort_t* vb      = (ushort_t*)alloc((size_t)HEADS*N*32*2);     // [H][N][32] bf16
  ushort_t* lgt     = (ushort_t*)alloc((size_t)N*12*2);           // [N][ET][H] bf16
  ushort_t* efb     = (ushort_t*)alloc((size_t)E*128*2);          // [E][128] bf16
  short*    Wt      = (short*)alloc((size_t)L*WTC*128*2);
  float*    sbias   = (float*)alloc((size_t)L*HEADS*NTYPES*32*4);
  if (o > ws_size) return;  // insufficient workspace: bail loudly (output stays wrong)

  hipMemsetAsync(cnt, 0, (size_t)EN*4, stream);

  hist_k<<<cdiv(NNZ,256),256,0,stream>>>(node_idx, edge_idx, cnt, ranks, E, NNZ);

  int nb = cdiv(EN,1024);
  scan_pass1<<<nb,1024,0,stream>>>(cnt, bsum, EN);
  scan_pass2<<<1,1024,0,stream>>>(bsum, nb);
  scan_pass3<<<nb,1024,0,stream>>>(cnt, bsum, off, EN);

  scatter_k<<<cdiv(NNZ,256),256,0,stream>>>(node_idx, edge_idx, ranks, off, srtE_rec, E, NNZ);

  wtprep_k<<<L*256,128,0,stream>>>(fc1_w, Wv, Wt, L);
  wqc_k<<<L*12,128,0,stream>>>(Wq, edge_ctx, Wt);
  sbias_k<<<L*HEADS*NTYPES,32,0,stream>>>(type_query, fc1_w, fc1_b, sbias);

  for (int l = 0; l < L; l++){
    const float* hin = (l == 0) ? x : ((const float*)d_out + 128);
    int hstride = (l == 0) ? DIN : (3*DIN);   // 128 or 384

    gemm_f3<<<cdiv(N,128),512,0,stream>>>(
        hin, hstride,
        Wt + (size_t)l*WTC*128,
        node_types,
        sbias + (size_t)l*HEADS*NTYPES*32,
        fc2_w + (size_t)l*HEADS*32,
        fc2_b + (size_t)l*HEADS,
        lgt, vb, N);

    k2b_f<<<E,256,0,stream>>>(lgt, vb, srtE_rec, off, cnt,
                              edge_type, efb, attn_rec, N, E);

    k2c<<<cdiv(N,4),256,0,stream>>>(attn_rec, off + E, cnt + E, NNZ, efb,
                                    hin, hstride,
                                    ln_g + (size_t)l*DIN, ln_b + (size_t)l*DIN,
                                    (float*)d_out, 3*DIN, DIN + l*DIN, (l == 0) ? 1 : 0, N, E);
  }
}

// Round 16
// 525.815 us; speedup vs baseline: 1.0165x; 1.0165x over previous
//
#include <hip/hip_runtime.h>
#include <math.h>

#define HEADS 4
#define HD 32      // per-head out dim
#define QD 64      // type query dim
#define DIN 128    // in_dim == hidden_dim
#define NTYPES 4
#define ETYPES 3
#define CAP 512    // per-edge LDS logit capacity (max segment ~85 for this data)
#define WTC 272    // Wt columns per layer: 0..127 fc1, 128..255 Wv, 256..267 Wqc(logit)

typedef __attribute__((ext_vector_type(8))) short bf16x8;
typedef __attribute__((ext_vector_type(4))) float f32x4;
typedef unsigned short ushort_t;

static inline int cdiv(int a, int b){ return (a + b - 1) / b; }

__device__ inline unsigned short f2bf(float f){
  unsigned u = __float_as_uint(f);
  unsigned r = (u + 0x7FFF + ((u >> 16) & 1)) >> 16;   // RNE
  return (unsigned short)r;
}
__device__ inline float bf2f(unsigned short u){ return __uint_as_float(((unsigned)u) << 16); }

// lgt layout: [n][et][h] bf16, row = 12 ushorts = 24B; one uint2 = all 4 heads of (n,et)
__device__ inline float lgt_get(const ushort_t* __restrict__ lgt, int n, int et, int hh){
  uint2 lg = *(const uint2*)((const char*)lgt + (size_t)n*24 + et*8);
  unsigned u = (hh & 2) ? lg.y : lg.x;
  return bf2f((hh & 1) ? (ushort_t)(u >> 16) : (ushort_t)(u & 0xffff));
}

// ---------------- preprocessing ----------------

// hist into concatenated [cnt_e | cnt_n] (size E+N); atomics double as sort ranks.
__global__ __launch_bounds__(256) void hist_k(const int* __restrict__ node_idx,
                                              const int* __restrict__ edge_idx,
                                              int* __restrict__ cnt,  // [E+N]
                                              uint2* __restrict__ ranks, int E, int NNZ)
{
  int i = blockIdx.x*256 + threadIdx.x;
  if (i < NNZ){
    unsigned re = (unsigned)atomicAdd(&cnt[edge_idx[i]], 1);
    unsigned rn = (unsigned)atomicAdd(&cnt[E + node_idx[i]], 1);
    uint2 r; r.x = re; r.y = rn;
    ranks[i] = r;
  }
}

__global__ __launch_bounds__(1024) void scan_pass1(const int* __restrict__ in, int* __restrict__ bsums, int n)
{
  __shared__ int sd[1024];
  int i = blockIdx.x*1024 + threadIdx.x;
  sd[threadIdx.x] = (i < n) ? in[i] : 0;
  __syncthreads();
  for (int s = 512; s > 0; s >>= 1){
    if (threadIdx.x < s) sd[threadIdx.x] += sd[threadIdx.x + s];
    __syncthreads();
  }
  if (threadIdx.x == 0) bsums[blockIdx.x] = sd[0];
}

__global__ __launch_bounds__(1024) void scan_pass2(int* __restrict__ bsums, int nb)
{
  __shared__ int sd[1024];
  int v = (threadIdx.x < nb) ? bsums[threadIdx.x] : 0;
  sd[threadIdx.x] = v;
  __syncthreads();
  for (int s = 1; s < 1024; s <<= 1){
    int t = (threadIdx.x >= s) ? sd[threadIdx.x - s] : 0;
    __syncthreads();
    sd[threadIdx.x] += t;
    __syncthreads();
  }
  if (threadIdx.x < nb) bsums[threadIdx.x] = sd[threadIdx.x] - v;  // exclusive
}

__global__ __launch_bounds__(1024) void scan_pass3(const int* __restrict__ in, const int* __restrict__ bsums,
                                                   int* __restrict__ out, int n)
{
  __shared__ int sd[1024];
  int i = blockIdx.x*1024 + threadIdx.x;
  int v = (i < n) ? in[i] : 0;
  sd[threadIdx.x] = v;
  __syncthreads();
  for (int s = 1; s < 1024; s <<= 1){
    int t = (threadIdx.x >= s) ? sd[threadIdx.x - s] : 0;
    __syncthreads();
    sd[threadIdx.x] += t;
    __syncthreads();
  }
  if (i < n) out[i] = bsums[blockIdx.x] + sd[threadIdx.x] - v;  // exclusive offsets
}

// Scatter: atomic-free; single scattered 8B store per entry.
// off is the concatenated exclusive scan: edge offsets at off[e], node offsets at off[E+n]-NNZ.
__global__ __launch_bounds__(256) void scatter_k(const int* __restrict__ node_idx, const int* __restrict__ edge_idx,
                                                 const uint2* __restrict__ ranks,
                                                 const int* __restrict__ off,
                                                 uint2* __restrict__ srtE_rec, int E, int NNZ)
{
  int i = blockIdx.x*256 + threadIdx.x;
  if (i >= NNZ) return;
  int n = node_idx[i], e = edge_idx[i];
  uint2 r = ranks[i];
  int pe = off[e] + (int)r.x;
  int pn = off[E + n] - NNZ + (int)r.y;
  uint2 rec; rec.x = (unsigned)n; rec.y = (unsigned)pn;
  srtE_rec[pe] = rec;
}

// ---------------- weight prep ----------------

// Wt cols 0..127: fc1 (hh=c>>5, j=c&31); 128..255: Wv
__global__ __launch_bounds__(128) void wtprep_k(const float* __restrict__ w1, const float* __restrict__ wv,
                                                short* __restrict__ Wt, int L)
{
  int c = blockIdx.x % 256, l = blockIdx.x / 256;
  int k = threadIdx.x;
  int hh = (c >> 5) & 3, j = c & 31;
  float v;
  if (c < 128) v = w1[((((size_t)l*HEADS + hh)*(DIN+QD)) + k)*32 + j];
  else         v = wv[((((size_t)l*HEADS + hh)*DIN) + k)*32 + j];
  Wt[((size_t)l*WTC + c)*128 + k] = (short)f2bf(v);
}

// Wqc logit columns: Wt[l][256 + h*3+et][k] = sum_d wq[l][h][k][d] * ec[l][h][et][d]
__global__ __launch_bounds__(128) void wqc_k(const float* __restrict__ wq, const float* __restrict__ ec,
                                             short* __restrict__ Wt)
{
  int b = blockIdx.x;                 // l*12 + h*3 + et
  int l = b / 12, c = b % 12, h = c / 3, et = c % 3;
  int k = threadIdx.x;
  const float* wrow = wq + ((((size_t)l*HEADS + h)*DIN) + k)*32;
  const float* ecp  = ec + (((size_t)l*HEADS + h)*ETYPES + et)*32;
  float s = 0.f;
  #pragma unroll
  for (int d = 0; d < 32; d++) s += wrow[d] * ecp[d];
  Wt[((size_t)l*WTC + 256 + c)*128 + k] = (short)f2bf(s);
}

// sbias[l][hh][ty][j] = b1 + sig @ w1[128:192]
__global__ __launch_bounds__(32) void sbias_k(const float* __restrict__ tq, const float* __restrict__ w1,
                                              const float* __restrict__ b1, float* __restrict__ sbias)
{
  int b = blockIdx.x;
  int ty = b % NTYPES; int hh = (b / NTYPES) % HEADS; int l = b / (NTYPES*HEADS);
  int j = threadIdx.x;
  const float* tqp = tq + (((size_t)l*HEADS + hh)*NTYPES + ty)*QD;
  const float* w1p = w1 + ((size_t)l*HEADS + hh)*(DIN+QD)*32;
  float s = b1[((size_t)l*HEADS + hh)*32 + j];
  for (int k = 0; k < QD; k++) s += tqp[k] * w1p[(size_t)(DIN + k)*32 + j];
  sbias[(size_t)b*32 + j] = s;
}

// ---------------- shared A-fragment loader ----------------

__device__ inline void load_afrag(const float* __restrict__ h, int hstride, int N,
                                  int rbase, int mf, int l15, int l4, int kk, bf16x8& a)
{
  int row = rbase + mf*16 + l15;
  int rr = (row < N) ? row : (N-1);
  const float* pa = h + (size_t)rr*hstride + kk*32 + l4*8;
  float4 f0 = *(const float4*)pa;
  float4 f1 = *(const float4*)(pa + 4);
  a[0] = (short)f2bf(f0.x); a[1] = (short)f2bf(f0.y);
  a[2] = (short)f2bf(f0.z); a[3] = (short)f2bf(f0.w);
  a[4] = (short)f2bf(f1.x); a[5] = (short)f2bf(f1.y);
  a[6] = (short)f2bf(f1.z); a[7] = (short)f2bf(f1.w);
}

// ---------------- gemmA: fc1 -> alpha (LDS) + fused logit columns -> lgt (R11-proven) ----------------

__global__ __launch_bounds__(256) void gemma_k(
    const float* __restrict__ h, int hstride,
    const short* __restrict__ Wt,          // this layer
    const int* __restrict__ node_types,
    const float* __restrict__ sbias,       // [H][NTYPES][32]
    const float* __restrict__ w2,          // [H][32]
    const float* __restrict__ b2,          // [H]
    ushort_t* __restrict__ lgt,            // [N][ET][H] bf16
    int N)
{
  __shared__ float alds[128][HEADS];
  int lane = threadIdx.x & 63, wvid = threadIdx.x >> 6;
  int wr = wvid >> 1, wc = wvid & 1;
  int l15 = lane & 15, l4 = lane >> 4;
  int rbase = blockIdx.x*128 + wr*64;

  f32x4 acc[4][4] = {};
  f32x4 acc_e[4] = {};

  #pragma unroll
  for (int kk = 0; kk < 4; kk++){
    bf16x8 a[4], b[4];
    #pragma unroll
    for (int mf = 0; mf < 4; mf++) load_afrag(h, hstride, N, rbase, mf, l15, l4, kk, a[mf]);
    #pragma unroll
    for (int cf = 0; cf < 4; cf++){
      int col = wc*64 + cf*16 + l15;
      b[cf] = *(const bf16x8*)(Wt + (size_t)col*128 + kk*32 + l4*8);
    }
    #pragma unroll
    for (int mf = 0; mf < 4; mf++)
      #pragma unroll
      for (int cf = 0; cf < 4; cf++)
        acc[mf][cf] = __builtin_amdgcn_mfma_f32_16x16x32_bf16(a[mf], b[cf], acc[mf][cf], 0, 0, 0);
    if (wc == 0){
      int ecol = 256 + ((l15 < 12) ? l15 : 11);
      bf16x8 be = *(const bf16x8*)(Wt + (size_t)ecol*128 + kk*32 + l4*8);
      #pragma unroll
      for (int mf = 0; mf < 4; mf++)
        acc_e[mf] = __builtin_amdgcn_mfma_f32_16x16x32_bf16(a[mf], be, acc_e[mf], 0, 0, 0);
    }
  }

  // fc1 epilogue -> alpha into LDS
  #pragma unroll
  for (int mf = 0; mf < 4; mf++){
    int rw[4], ty[4];
    #pragma unroll
    for (int r = 0; r < 4; r++){
      rw[r] = rbase + mf*16 + l4*4 + r;
      ty[r] = (rw[r] < N) ? node_types[rw[r]] : 0;
    }
    #pragma unroll
    for (int p = 0; p < 2; p++){
      int hh = wc*2 + p;
      float w2a = w2[hh*32 + l15];
      float w2b = w2[hh*32 + 16 + l15];
      float b2v = b2[hh];
      #pragma unroll
      for (int r = 0; r < 4; r++){
        const float* sb = sbias + ((size_t)hh*NTYPES + ty[r])*32;
        float z0 = acc[mf][2*p  ][r] + sb[l15];
        float z1 = acc[mf][2*p+1][r] + sb[16 + l15];
        float t0 = 1.f - 2.f/(__expf(2.f*z0) + 1.f);   // tanh
        float t1 = 1.f - 2.f/(__expf(2.f*z1) + 1.f);
        float val = t0*w2a + t1*w2b;
        val += __shfl_xor(val, 1); val += __shfl_xor(val, 2);
        val += __shfl_xor(val, 4); val += __shfl_xor(val, 8);
        if (l15 == 0)
          alds[wr*64 + mf*16 + l4*4 + r][hh] = 1.f/(1.f + __expf(-(val + b2v)));
      }
    }
  }
  __syncthreads();

  // logit epilogue (wc==0 waves own acc_e); D frag: row = l4*4+r, col = l15
  if (wc == 0 && l15 < 12){
    int hq = l15 / 3, et = l15 % 3;
    #pragma unroll
    for (int mf = 0; mf < 4; mf++){
      #pragma unroll
      for (int r = 0; r < 4; r++){
        int rowloc = wr*64 + mf*16 + l4*4 + r;
        int row = blockIdx.x*128 + rowloc;
        if (row < N){
          float s = acc_e[mf][r] * alds[rowloc][hq];
          s = (s >= 0.f) ? s : 0.2f*s;
          lgt[(size_t)row*12 + et*4 + hq] = f2bf(s);
        }
      }
    }
  }
}

// ---------------- gemmV: h @ Wv -> vb[h][n][32] bf16 (R11-proven) ----------------

__global__ __launch_bounds__(256) void gemmv_k(
    const float* __restrict__ h, int hstride,
    const short* __restrict__ Wt,
    ushort_t* __restrict__ vb,             // [H][N][32]
    int N)
{
  int lane = threadIdx.x & 63, wvid = threadIdx.x >> 6;
  int wr = wvid >> 1, wc = wvid & 1;
  int l15 = lane & 15, l4 = lane >> 4;
  int rbase = blockIdx.x*128 + wr*64;

  f32x4 acc[4][4] = {};

  #pragma unroll
  for (int kk = 0; kk < 4; kk++){
    bf16x8 a[4], b[4];
    #pragma unroll
    for (int mf = 0; mf < 4; mf++) load_afrag(h, hstride, N, rbase, mf, l15, l4, kk, a[mf]);
    #pragma unroll
    for (int cf = 0; cf < 4; cf++){
      int col = 128 + wc*64 + cf*16 + l15;
      b[cf] = *(const bf16x8*)(Wt + (size_t)col*128 + kk*32 + l4*8);
    }
    #pragma unroll
    for (int mf = 0; mf < 4; mf++)
      #pragma unroll
      for (int cf = 0; cf < 4; cf++)
        acc[mf][cf] = __builtin_amdgcn_mfma_f32_16x16x32_bf16(a[mf], b[cf], acc[mf][cf], 0, 0, 0);
  }

  #pragma unroll
  for (int mf = 0; mf < 4; mf++){
    #pragma unroll
    for (int r = 0; r < 4; r++){
      int row = rbase + mf*16 + l4*4 + r;
      if (row < N){
        #pragma unroll
        for (int cf = 0; cf < 4; cf++){
          int c = wc*64 + cf*16 + l15;        // 0..127
          int hh = c >> 5, d = c & 31;
          vb[((size_t)hh*N + row)*32 + d] = f2bf(acc[mf][cf][r]);
        }
      }
    }
  }
}

// ---------------- k2b fused: cooperative logit load + segment softmax + edge_feat + attn scatter ----------------
// attn_rec[pn] = {e, a0|a1, a2|a3, 0}; efb [E][128] bf16.

__global__ __launch_bounds__(256) void k2b_f(
    const ushort_t* __restrict__ lgt, const ushort_t* __restrict__ vb,
    const uint2* __restrict__ srtE_rec, const int* __restrict__ edge_off, const int* __restrict__ cnt_e,
    const int* __restrict__ edge_type,
    ushort_t* __restrict__ efb,            // [E][128] bf16
    uint4* __restrict__ attn_rec,          // [NNZ] {e, a01, a23, 0}
    int N, int E)
{
  __shared__ float lbuf[HEADS][CAP];
  __shared__ int   nbuf[CAP];
  __shared__ int   pnbuf[CAP];
  __shared__ float mi[HEADS][2];

  int e = blockIdx.x;
  int off = edge_off[e], cnt = cnt_e[e];
  if (cnt == 0) return;
  int lane = threadIdx.x & 63, hh = threadIdx.x >> 6;
  int g = lane & 15, grp = lane >> 4;
  int et = edge_type[e];

  if (cnt <= CAP){
    // phase A: ALL 256 threads split entries; one srtE_rec + one lgt uint2 per entry
    for (int j = threadIdx.x; j < cnt; j += 256){
      uint2 rc = srtE_rec[off + j];
      uint2 lg = *(const uint2*)((const char*)lgt + (size_t)rc.x*24 + et*8);
      lbuf[0][j] = bf2f((ushort_t)(lg.x & 0xffff));
      lbuf[1][j] = bf2f((ushort_t)(lg.x >> 16));
      lbuf[2][j] = bf2f((ushort_t)(lg.y & 0xffff));
      lbuf[3][j] = bf2f((ushort_t)(lg.y >> 16));
      nbuf[j] = (int)rc.x;
      pnbuf[j] = (int)rc.y;
    }
    __syncthreads();

    // per-wave max over this head's logits (LDS sweep)
    float mloc = -INFINITY;
    for (int j = lane; j < cnt; j += 64) mloc = fmaxf(mloc, lbuf[hh][j]);
    #pragma unroll
    for (int sh = 32; sh > 0; sh >>= 1) mloc = fmaxf(mloc, __shfl_xor(mloc, sh));
    float m = mloc;

    // phase B: exp-sum + V accumulate; 4-deep unroll, clamped indices
    float ef0 = 0.f, ef1 = 0.f, ssum = 0.f;
    const int cm1 = cnt - 1;
    const ushort_t* vbh = vb + (size_t)hh*N*32;
    for (int jj = 0; jj < cnt; jj += 16){
      int j0 = jj + grp, j1 = j0 + 4, j2 = j0 + 8, j3 = j0 + 12;
      int n0 = nbuf[(j0 < cm1) ? j0 : cm1];
      int n1 = nbuf[(j1 < cm1) ? j1 : cm1];
      int n2 = nbuf[(j2 < cm1) ? j2 : cm1];
      int n3 = nbuf[(j3 < cm1) ? j3 : cm1];
      unsigned w0 = *(const unsigned*)&vbh[(size_t)n0*32 + 2*g];
      unsigned w1 = *(const unsigned*)&vbh[(size_t)n1*32 + 2*g];
      unsigned w2 = *(const unsigned*)&vbh[(size_t)n2*32 + 2*g];
      unsigned w3 = *(const unsigned*)&vbh[(size_t)n3*32 + 2*g];
      float e0 = (j0 < cnt) ? __expf(lbuf[hh][j0] - m) : 0.f;
      float e1 = (j1 < cnt) ? __expf(lbuf[hh][j1] - m) : 0.f;
      float e2 = (j2 < cnt) ? __expf(lbuf[hh][j2] - m) : 0.f;
      float e3 = (j3 < cnt) ? __expf(lbuf[hh][j3] - m) : 0.f;
      ef0 += e0*bf2f((ushort_t)(w0 & 0xffff)) + e1*bf2f((ushort_t)(w1 & 0xffff))
           + e2*bf2f((ushort_t)(w2 & 0xffff)) + e3*bf2f((ushort_t)(w3 & 0xffff));
      ef1 += e0*bf2f((ushort_t)(w0 >> 16)) + e1*bf2f((ushort_t)(w1 >> 16))
           + e2*bf2f((ushort_t)(w2 >> 16)) + e3*bf2f((ushort_t)(w3 >> 16));
      ssum += e0 + e1 + e2 + e3;
    }
    ef0 += __shfl_xor(ef0, 16); ef0 += __shfl_xor(ef0, 32);
    ef1 += __shfl_xor(ef1, 16); ef1 += __shfl_xor(ef1, 32);
    ssum += __shfl_xor(ssum, 16); ssum += __shfl_xor(ssum, 32);
    float inv = 1.0f / ssum;
    if (grp == 0){
      unsigned w = (unsigned)f2bf(ef0*inv) | ((unsigned)f2bf(ef1*inv) << 16);
      *(unsigned*)&efb[(size_t)e*128 + hh*32 + 2*g] = w;
    }
    if (lane == 0){ mi[hh][0] = m; mi[hh][1] = inv; }
    __syncthreads();

    // phase C: wave 0 packs {e, 4-head attn}, one 16B scattered store per entry
    if (hh == 0){
      for (int j = lane; j < cnt; j += 64){
        int pn = pnbuf[j];
        float a0 = __expf(lbuf[0][j] - mi[0][0]) * mi[0][1];
        float a1 = __expf(lbuf[1][j] - mi[1][0]) * mi[1][1];
        float a2 = __expf(lbuf[2][j] - mi[2][0]) * mi[2][1];
        float a3 = __expf(lbuf[3][j] - mi[3][0]) * mi[3][1];
        uint4 o;
        o.x = (unsigned)e;
        o.y = (unsigned)f2bf(a0) | ((unsigned)f2bf(a1) << 16);
        o.z = (unsigned)f2bf(a2) | ((unsigned)f2bf(a3) << 16);
        o.w = 0u;
        attn_rec[pn] = o;
      }
    }
  } else {
    // slow path (cnt > CAP): logits are loads, so just re-load per pass
    float mloc = -INFINITY;
    for (int j = lane; j < cnt; j += 64)
      mloc = fmaxf(mloc, lgt_get(lgt, (int)srtE_rec[off + j].x, et, hh));
    #pragma unroll
    for (int sh = 32; sh > 0; sh >>= 1) mloc = fmaxf(mloc, __shfl_xor(mloc, sh));
    float m = mloc;

    float ef0 = 0.f, ef1 = 0.f, ssum = 0.f;
    for (int jj = 0; jj < cnt; jj += 4){
      int j = jj + grp;
      if (j < cnt){
        int n = (int)srtE_rec[off + j].x;
        float ex = __expf(lgt_get(lgt, n, et, hh) - m);
        unsigned vw = *(const unsigned*)&vb[((size_t)hh*N + n)*32 + 2*g];
        ef0 += ex * bf2f((unsigned short)(vw & 0xffff));
        ef1 += ex * bf2f((unsigned short)(vw >> 16));
        ssum += ex;
      }
    }
    ef0 += __shfl_xor(ef0, 16); ef0 += __shfl_xor(ef0, 32);
    ef1 += __shfl_xor(ef1, 16); ef1 += __shfl_xor(ef1, 32);
    ssum += __shfl_xor(ssum, 16); ssum += __shfl_xor(ssum, 32);
    float inv = 1.0f / ssum;
    if (grp == 0){
      unsigned w = (unsigned)f2bf(ef0*inv) | ((unsigned)f2bf(ef1*inv) << 16);
      *(unsigned*)&efb[(size_t)e*128 + hh*32 + 2*g] = w;
    }
    for (int j = lane; j < cnt; j += 64){
      uint2 rc = srtE_rec[off + j];
      float ex = __expf(lgt_get(lgt, (int)rc.x, et, hh) - m);
      ushort_t* p = (ushort_t*)&attn_rec[rc.y];
      p[2 + hh] = f2bf(ex * inv);
      if (hh == 0){
        ((unsigned*)p)[0] = (unsigned)e;
        ((unsigned*)p)[3] = 0u;
      }
    }
  }
}

// ---------------- K2c: wave-per-node: shfl-batched gather + residual + wave LayerNorm ----------------
// Layer 0 additionally writes the x-copy into out cols 0..127.

__global__ __launch_bounds__(256) void k2c(
    const uint4* __restrict__ attn_rec,
    const int* __restrict__ node_off, const int* __restrict__ cnt_n, int noff_shift,
    const ushort_t* __restrict__ efb,      // [E][128]
    const float* __restrict__ h_in, int hstride,
    const float* __restrict__ ln_g, const float* __restrict__ ln_b,
    float* __restrict__ out, int out_stride, int out_col, int do_xcopy, int N, int E)
{
  int wv = threadIdx.x >> 6, lane = threadIdx.x & 63;
  int n = blockIdx.x*4 + wv;
  if (n >= N) return;
  int off = node_off[n] - noff_shift, cnt = cnt_n[n];
  int hh = lane >> 4;                 // head owning dims {2*lane, 2*lane+1}
  float nf0 = 0.f, nf1 = 0.f;

  for (int j0 = 0; j0 < cnt; j0 += 8){
    int mm = cnt - j0; if (mm > 8) mm = 8;
    uint4 rc = make_uint4(0u, 0u, 0u, 0u);
    if (lane < mm) rc = attn_rec[off + j0 + lane];
    unsigned w[8]; float av[8];
    #pragma unroll
    for (int j = 0; j < 8; j++){
      unsigned ej = (unsigned)__shfl((int)rc.x, j);
      unsigned ay = (unsigned)__shfl((int)rc.y, j);
      unsigned az = (unsigned)__shfl((int)rc.z, j);
      unsigned u = (hh & 2) ? az : ay;
      float a = bf2f((hh & 1) ? (ushort_t)(u >> 16) : (ushort_t)(u & 0xffff));
      av[j] = (j < mm) ? a : 0.f;
      w[j] = *(const unsigned*)&efb[(size_t)ej*128 + 2*lane];
    }
    #pragma unroll
    for (int j = 0; j < 8; j++){
      nf0 += av[j] * bf2f((ushort_t)(w[j] & 0xffff));
      nf1 += av[j] * bf2f((ushort_t)(w[j] >> 16));
    }
  }

  float2 hr = *(const float2*)&h_in[(size_t)n*hstride + 2*lane];
  if (do_xcopy)
    *(float2*)&out[(size_t)n*out_stride + 2*lane] = hr;   // x into cols 0..127
  float hn0 = nf0 + hr.x, hn1 = nf1 + hr.y;

  float s = hn0 + hn1;
  #pragma unroll
  for (int sh = 32; sh > 0; sh >>= 1) s += __shfl_xor(s, sh);
  float mu = s * (1.0f/128.0f);
  float d0 = hn0 - mu, d1 = hn1 - mu;
  float s2 = d0*d0 + d1*d1;
  #pragma unroll
  for (int sh = 32; sh > 0; sh >>= 1) s2 += __shfl_xor(s2, sh);
  float r = rsqrtf(s2*(1.0f/128.0f) + 1e-5f);

  float2 g2 = *(const float2*)&ln_g[2*lane];
  float2 b2 = *(const float2*)&ln_b[2*lane];
  float2 o2;
  o2.x = d0*r*g2.x + b2.x;
  o2.y = d1*r*g2.y + b2.y;
  *(float2*)&out[(size_t)n*out_stride + out_col + 2*lane] = o2;
}

// ---------------- launcher ----------------

extern "C" void kernel_launch(void* const* d_in, const int* in_sizes, int n_in,
                              void* d_out, int out_size, void* d_ws, size_t ws_size,
                              hipStream_t stream)
{
  const float* x          = (const float*)d_in[0];
  const int*   node_types = (const int*)  d_in[1];
  const int*   node_idx   = (const int*)  d_in[2];
  const int*   edge_idx   = (const int*)  d_in[3];
  const int*   edge_type  = (const int*)  d_in[4];
  const float* type_query = (const float*)d_in[5];
  const float* fc1_w      = (const float*)d_in[6];
  const float* fc1_b      = (const float*)d_in[7];
  const float* fc2_w      = (const float*)d_in[8];
  const float* fc2_b      = (const float*)d_in[9];
  const float* Wq         = (const float*)d_in[10];
  const float* Wv         = (const float*)d_in[11];
  const float* edge_ctx   = (const float*)d_in[12];
  const float* ln_g       = (const float*)d_in[13];
  const float* ln_b       = (const float*)d_in[14];

  const int N   = in_sizes[1];
  const int NNZ = in_sizes[2];
  const int E   = in_sizes[4];
  const int L   = 2;
  const int EN  = E + N;

  char* ws = (char*)d_ws;
  size_t o = 0;
  auto alloc = [&](size_t bytes)->void*{
    void* p = ws + o;
    o = (o + bytes + 255) & ~(size_t)255;
    return p;
  };
  int* cnt       = (int*)alloc((size_t)EN*4);       // [cnt_e | cnt_n]
  int* off       = (int*)alloc((size_t)(EN+1)*4);   // concatenated exclusive scan
  uint2* ranks   = (uint2*)alloc((size_t)NNZ*8);
  uint2* srtE_rec= (uint2*)alloc((size_t)NNZ*8);
  int* bsum      = (int*)alloc((size_t)1024*4);
  uint4* attn_rec = (uint4*)alloc((size_t)NNZ*16);                // [NNZ] {e,a01,a23,0}
  ushort_t* vb      = (ushort_t*)alloc((size_t)HEADS*N*32*2);     // [H][N][32] bf16
  ushort_t* lgt     = (ushort_t*)alloc((size_t)N*12*2);           // [N][ET][H] bf16
  ushort_t* efb     = (ushort_t*)alloc((size_t)E*128*2);          // [E][128] bf16
  short*    Wt      = (short*)alloc((size_t)L*WTC*128*2);
  float*    sbias   = (float*)alloc((size_t)L*HEADS*NTYPES*32*4);
  if (o > ws_size) return;  // insufficient workspace: bail loudly (output stays wrong)

  hipMemsetAsync(cnt, 0, (size_t)EN*4, stream);

  hist_k<<<cdiv(NNZ,256),256,0,stream>>>(node_idx, edge_idx, cnt, ranks, E, NNZ);

  int nb = cdiv(EN,1024);
  scan_pass1<<<nb,1024,0,stream>>>(cnt, bsum, EN);
  scan_pass2<<<1,1024,0,stream>>>(bsum, nb);
  scan_pass3<<<nb,1024,0,stream>>>(cnt, bsum, off, EN);

  scatter_k<<<cdiv(NNZ,256),256,0,stream>>>(node_idx, edge_idx, ranks, off, srtE_rec, E, NNZ);

  wtprep_k<<<L*256,128,0,stream>>>(fc1_w, Wv, Wt, L);
  wqc_k<<<L*12,128,0,stream>>>(Wq, edge_ctx, Wt);
  sbias_k<<<L*HEADS*NTYPES,32,0,stream>>>(type_query, fc1_w, fc1_b, sbias);

  for (int l = 0; l < L; l++){
    const float* hin = (l == 0) ? x : ((const float*)d_out + 128);
    int hstride = (l == 0) ? DIN : (3*DIN);   // 128 or 384

    gemma_k<<<cdiv(N,128),256,0,stream>>>(
        hin, hstride,
        Wt + (size_t)l*WTC*128,
        node_types,
        sbias + (size_t)l*HEADS*NTYPES*32,
        fc2_w + (size_t)l*HEADS*32,
        fc2_b + (size_t)l*HEADS,
        lgt, N);

    gemmv_k<<<cdiv(N,128),256,0,stream>>>(
        hin, hstride,
        Wt + (size_t)l*WTC*128,
        vb, N);

    k2b_f<<<E,256,0,stream>>>(lgt, vb, srtE_rec, off, cnt,
                              edge_type, efb, attn_rec, N, E);

    k2c<<<cdiv(N,4),256,0,stream>>>(attn_rec, off + E, cnt + E, NNZ, efb,
                                    hin, hstride,
                                    ln_g + (size_t)l*DIN, ln_b + (size_t)l*DIN,
                                    (float*)d_out, 3*DIN, DIN + l*DIN, (l == 0) ? 1 : 0, N, E);
  }
}